// Round 15
// baseline (271.198 us; speedup 1.0000x reference)
//
#include <hip/hip_runtime.h>
#include <hip/hip_fp8.h>
#include <math.h>

#define H 8
#define NBLKA 512          // #chunks for scatter pass (12.5K edges/chunk)
#define BTH 1024           // threads for scatter
#define SCHK 12544         // LDS chunk capacity for scatter staging
#define BSH 8              // 256 nodes per bucket
#define BCAP 9216          // per-bucket slot capacity (mean 8184 + 11 sigma for E=6.4M)
#define TS 1024            // threads for fused sort+layer1 (4 lanes/node)
#define POOLG 128          // max graphs spanned per block in pooling fast path

// ---- fp8 e4m3 helpers via HIP type (HW cvt on gfx950) ----
__device__ __forceinline__ unsigned f2fp8(float f) {
    __hip_fp8_e4m3 q(f);
    return (unsigned)q.__x;
}
__device__ __forceinline__ float fp8f(unsigned v) {
    __hip_fp8_e4m3 q;
    q.__x = (__hip_fp8_storage_t)v;
    return (float)q;
}
__device__ __forceinline__ void acc8(float* a, uint2 v) {
    a[0] += fp8f(v.x & 255u);         a[1] += fp8f((v.x >> 8) & 255u);
    a[2] += fp8f((v.x >> 16) & 255u); a[3] += fp8f(v.x >> 24);
    a[4] += fp8f(v.y & 255u);         a[5] += fp8f((v.y >> 8) & 255u);
    a[6] += fp8f((v.y >> 16) & 255u); a[7] += fp8f(v.y >> 24);
}

// ====== Phase A: single-read scatter — stage chunk in LDS, count, reserve, sort, copy out ======
// ei is read ONCE (R14 read dst twice: count pass + scatter pass). All sorting from LDS.
__global__ __launch_bounds__(BTH) void scatterK(const int* __restrict__ ei, int E, int NB,
                                                int chunk, int* __restrict__ cursor,
                                                unsigned* __restrict__ packed) {
    __shared__ unsigned pk[SCHK];             // packed word per staged edge
    __shared__ unsigned short bk[SCHK];       // bucket id per staged edge
    __shared__ unsigned ss[SCHK];             // bucket-sorted output
    __shared__ int cnt[1024], sc[1024], base[1024], cur[1024];
    int t = threadIdx.x, blk = blockIdx.x;
    cnt[t] = 0;
    __syncthreads();
    int s = blk * chunk, e = min(E, s + chunk);
    int n = e - s;
    // single pass over ei: stage + count
    for (int i = t; i < n; i += BTH) {
        int src = __builtin_nontemporal_load(ei + s + i);
        int dst = __builtin_nontemporal_load(ei + E + s + i);
        int b = dst >> BSH;
        pk[i] = ((unsigned)src << 8) | (unsigned)(dst & 255);
        bk[i] = (unsigned short)b;
        atomicAdd(&cnt[b], 1);
    }
    __syncthreads();
    int c = cnt[t];
    sc[t] = c;
    __syncthreads();
    for (int off = 1; off < 1024; off <<= 1) {
        int v = (t >= off) ? sc[t - off] : 0;
        __syncthreads();
        sc[t] += v;
        __syncthreads();
    }
    cur[t] = sc[t] - c;                       // local exclusive start
    base[t] = (t < NB && c > 0) ? atomicAdd(&cursor[t], c) : 0;
    __syncthreads();
    // LDS -> LDS bucket sort
    for (int i = t; i < n; i += BTH) {
        int pos = atomicAdd(&cur[bk[i]], 1);
        ss[pos] = pk[i];
    }
    __syncthreads();
    // copy-out: wave per bucket, lane per element -> coalesced full lines
    int wave = t >> 6, lane = t & 63;
    for (int j = wave; j < NB; j += (BTH >> 6)) {
        int nj = cnt[j];
        int ls = sc[j] - nj;
        int bs = base[j];
        int m = min(nj, BCAP - bs);           // capacity guard (never hit for random dst)
        int gs = j * BCAP + bs;
        for (int k = lane; k < m; k += 64)
            packed[gs + k] = ss[ls + k];
    }
}

// ====== Phase B fused: single-read in-bucket sort (LDS->LDS) + layer-1 MLP -> h1 fp8 ======
__global__ void sortL1K(unsigned* __restrict__ packed, const int* __restrict__ bucketCnt,
                        const float* __restrict__ x, int N,
                        const float* __restrict__ W1a, const float* __restrict__ b1a,
                        const float* __restrict__ W1b, const float* __restrict__ b1b,
                        int* __restrict__ nodeStart, uint2* __restrict__ h1) {
    __shared__ unsigned raw[BCAP];            // staged packed words (single global read)
    __shared__ unsigned ss[BCAP];             // exact-dst sorted srcs
    __shared__ int cnt[256], sb[256], cur[256];
    __shared__ float sW1a[H], sb1a[H], sW1b[H * H], sb1b[H];
    int t = threadIdx.x, b = blockIdx.x;
    if (t < 256) cnt[t] = 0;
    else if (t < 256 + H) { int j = t - 256; sW1a[j] = W1a[j]; sb1a[j] = b1a[j]; sb1b[j] = b1b[j]; }
    else if (t < 256 + H + H * H) { int j = t - 256 - H; sW1b[j] = W1b[j]; }
    __syncthreads();
    int s = b * BCAP;
    int n_e = min(bucketCnt[b], BCAP);
    // single global read: stage + count exact dst
    for (int i = t; i < n_e; i += TS) {
        unsigned p = __builtin_nontemporal_load(packed + s + i);
        raw[i] = p;
        atomicAdd(&cnt[p & 255u], 1);
    }
    __syncthreads();
    if (t < 256) sb[t] = cnt[t];
    __syncthreads();
    for (int off = 1; off < 256; off <<= 1) {
        int add = (t < 256 && t >= off) ? sb[t - off] : 0;
        __syncthreads();
        if (t < 256) sb[t] += add;
        __syncthreads();
    }
    if (t < 256) {
        int excl = sb[t] - cnt[t];
        cur[t] = excl;
        nodeStart[(b << BSH) + t] = s + excl;
    }
    __syncthreads();
    // LDS -> LDS scatter into exact-dst order
    for (int i = t; i < n_e; i += TS) {
        unsigned p = raw[i];
        int pos = atomicAdd(&cur[p & 255u], 1);
        ss[pos] = p >> 8;
    }
    __syncthreads();
    // write back sorted srcs for layer2K (coalesced)
    for (int i = t; i < n_e; i += TS) packed[s + i] = ss[i];
    // layer-1: 4 lanes/node; gather x[src], unroll x4 for 4 loads in flight per wave
    int node = t >> 2, q4 = t & 3;
    int gn = (b << BSH) + node;
    int lo = sb[node] - cnt[node], hi = sb[node];
    float sum = 0.f;
    for (int k = lo + q4; k < hi; k += 16) {
        int k1 = k + 4, k2 = k + 8, k3 = k + 12;
        unsigned i0 = ss[k];
        unsigned i1 = ss[min(k1, hi - 1)];
        unsigned i2 = ss[min(k2, hi - 1)];
        unsigned i3 = ss[min(k3, hi - 1)];
        float x0 = x[i0], x1 = x[i1], x2 = x[i2], x3 = x[i3];
        sum += x0;
        if (k1 < hi) sum += x1;
        if (k2 < hi) sum += x2;
        if (k3 < hi) sum += x3;
    }
    sum += __shfl_xor(sum, 1, 64);
    sum += __shfl_xor(sum, 2, 64);
    if (q4 == 0 && gn < N) {
        float z = x[gn] + sum;
        float tv[H];
#pragma unroll
        for (int k = 0; k < H; k++) tv[k] = fmaxf(fmaf(z, sW1a[k], sb1a[k]), 0.f);
        float hv[H];
#pragma unroll
        for (int j = 0; j < H; j++) {
            float a = sb1b[j];
#pragma unroll
            for (int k = 0; k < H; k++) a += tv[k] * sW1b[k * H + j];
            hv[j] = a > 0.f ? a : (expf(a) - 1.f);   // elu
        }
        uint2 o;
        o.x = f2fp8(hv[0]) | (f2fp8(hv[1]) << 8) | (f2fp8(hv[2]) << 16) | (f2fp8(hv[3]) << 24);
        o.y = f2fp8(hv[4]) | (f2fp8(hv[5]) << 8) | (f2fp8(hv[6]) << 16) | (f2fp8(hv[7]) << 24);
        h1[gn] = o;
    }
}

// ====== Phase C: layer-2, LDS-staged index list + unroll-x4 gather (R14-exact) ======
__global__ __launch_bounds__(1024) void layer2K(
        const unsigned* __restrict__ packed, const int* __restrict__ nodeStart,
        const int* __restrict__ bucketCnt, const uint2* __restrict__ h1, int N,
        const float* __restrict__ W2a, const float* __restrict__ b2a,
        const float* __restrict__ W2b, const float* __restrict__ b2b,
        const int* __restrict__ batch, float* __restrict__ sumsCnt) {
    __shared__ unsigned ss[BCAP];
    __shared__ int sNS[257];
    __shared__ float pool[POOLG * 9];
    __shared__ float sW2a[H * H], sb2a[H], sW2b[H * H], sb2b[H];
    int t = threadIdx.x, b = blockIdx.x;
    int s = b * BCAP;
    int n_e = min(bucketCnt[b], BCAP);
    for (int i = t; i < n_e; i += 1024)
        ss[i] = __builtin_nontemporal_load(packed + s + i);
    if (t < 256) sNS[t] = nodeStart[(b << BSH) + t] - s;
    if (t == 256) sNS[256] = 0;               // patched below
    if (t < H) { sb2a[t] = b2a[t]; sb2b[t] = b2b[t]; }
    else if (t >= 64 && t < 64 + H * H) sW2a[t - 64] = W2a[t - 64];
    else if (t >= 192 && t < 192 + H * H) sW2b[t - 192] = W2b[t - 192];
    __syncthreads();
    if (t == 0) sNS[256] = n_e;
    __syncthreads();
    int node = t >> 2, q4 = t & 3;
    int gn = (b << BSH) + node;
    int lo = sNS[node], hi = sNS[node + 1];
    float a[H] = {0.f, 0.f, 0.f, 0.f, 0.f, 0.f, 0.f, 0.f};
    for (int k = lo + q4; k < hi; k += 16) {
        int k1 = k + 4, k2 = k + 8, k3 = k + 12;
        unsigned i0 = ss[k];
        unsigned i1 = ss[min(k1, hi - 1)];
        unsigned i2 = ss[min(k2, hi - 1)];
        unsigned i3 = ss[min(k3, hi - 1)];
        uint2 v0 = h1[i0];
        uint2 v1 = h1[i1];
        uint2 v2 = h1[i2];
        uint2 v3 = h1[i3];
        acc8(a, v0);
        if (k1 < hi) acc8(a, v1);
        if (k2 < hi) acc8(a, v2);
        if (k3 < hi) acc8(a, v3);
    }
#pragma unroll
    for (int j = 0; j < H; j++) {
        a[j] += __shfl_xor(a[j], 1, 64);
        a[j] += __shfl_xor(a[j], 2, 64);
    }
    bool valid = (q4 == 0) && (gn < N);
    float h2[H];
    int g = 0;
    if (valid) {
        uint2 v = h1[gn];
        float z[H] = {fp8f(v.x & 255u) + a[0],         fp8f((v.x >> 8) & 255u) + a[1],
                      fp8f((v.x >> 16) & 255u) + a[2], fp8f(v.x >> 24) + a[3],
                      fp8f(v.y & 255u) + a[4],         fp8f((v.y >> 8) & 255u) + a[5],
                      fp8f((v.y >> 16) & 255u) + a[6], fp8f(v.y >> 24) + a[7]};
        float tv[H];
#pragma unroll
        for (int k = 0; k < H; k++) {
            float acc = sb2a[k];
#pragma unroll
            for (int j = 0; j < H; j++) acc += z[j] * sW2a[j * H + k];
            tv[k] = fmaxf(acc, 0.f);
        }
#pragma unroll
        for (int j = 0; j < H; j++) {
            float acc = sb2b[j];
#pragma unroll
            for (int k = 0; k < H; k++) acc += tv[k] * sW2b[k * H + j];
            h2[j] = acc;
        }
        g = batch[gn];
    }
    int gfirst = batch[min(b << BSH, N - 1)];
    int glast  = batch[min((b << BSH) + 255, N - 1)];
    int span = glast - gfirst + 1;
    if (span <= POOLG) {
        int span9 = span * 9;
        for (int j = t; j < span9; j += 1024) pool[j] = 0.f;
        __syncthreads();
        if (valid) {
            float* p = &pool[(g - gfirst) * 9];
#pragma unroll
            for (int j = 0; j < H; j++) atomicAdd(p + j, h2[j]);
            atomicAdd(p + 8, 1.f);
        }
        __syncthreads();
        for (int j = t; j < span9; j += 1024)
            atomicAdd(&sumsCnt[(size_t)gfirst * 9 + j], pool[j]);
    } else if (valid) {
        float* p = &sumsCnt[(size_t)g * 9];
#pragma unroll
        for (int j = 0; j < H; j++) atomicAdd(p + j, h2[j]);
        atomicAdd(p + 8, 1.f);
    }
}

__global__ void finalK(const float* __restrict__ sumsCnt, const float* __restrict__ Wfc,
                       const float* __restrict__ bfc, float* __restrict__ out, int G) {
    int g = blockIdx.x * blockDim.x + threadIdx.x;
    if (g >= G) return;
    const float* s = &sumsCnt[(size_t)g * 9];
    float c = fmaxf(s[8], 1.f);
    float dot = 0.f;
#pragma unroll
    for (int j = 0; j < H; j++) dot += s[j] * Wfc[j];
    float a = dot / c + bfc[0];
    out[g] = 1.f / (1.f + expf(-a));
}

// ============================ FALLBACK (R1 atomic path) ============================
__global__ void edge_agg1(const int* __restrict__ ei, const float* __restrict__ x,
                          float* __restrict__ agg1, int E) {
    int e = blockIdx.x * blockDim.x + threadIdx.x;
    if (e >= E) return;
    atomicAdd(&agg1[ei[E + e]], x[ei[e]]);
}
__global__ void node1F(const float* __restrict__ x, const float* __restrict__ agg1,
                       const float* __restrict__ W1a, const float* __restrict__ b1a,
                       const float* __restrict__ W1b, const float* __restrict__ b1b,
                       float* __restrict__ h1, int N) {
    int n = blockIdx.x * blockDim.x + threadIdx.x;
    if (n >= N) return;
    float z = x[n] + agg1[n];
    float tv[H];
#pragma unroll
    for (int k = 0; k < H; k++) tv[k] = fmaxf(z * W1a[k] + b1a[k], 0.f);
#pragma unroll
    for (int j = 0; j < H; j++) {
        float acc = b1b[j];
#pragma unroll
        for (int k = 0; k < H; k++) acc += tv[k] * W1b[k * H + j];
        h1[(size_t)n * H + j] = acc > 0.f ? acc : (expf(acc) - 1.f);
    }
}
__global__ void edge_agg2(const int* __restrict__ ei, const float* __restrict__ h1,
                          float* __restrict__ agg2, int E) {
    long long i = (long long)blockIdx.x * blockDim.x + threadIdx.x;
    if (i >= (long long)E * H) return;
    int e = (int)(i >> 3), k = (int)(i & 7);
    atomicAdd(&agg2[(size_t)ei[E + e] * H + k], h1[(size_t)ei[e] * H + k]);
}
__global__ void node2F(const float* __restrict__ h1, const float* __restrict__ agg2,
                       const float* __restrict__ W2a, const float* __restrict__ b2a,
                       const float* __restrict__ W2b, const float* __restrict__ b2b,
                       const int* __restrict__ batch,
                       float* __restrict__ sums, float* __restrict__ counts, int N) {
    int n = blockIdx.x * blockDim.x + threadIdx.x;
    if (n >= N) return;
    float z[H], tv[H];
#pragma unroll
    for (int j = 0; j < H; j++) z[j] = h1[(size_t)n * H + j] + agg2[(size_t)n * H + j];
#pragma unroll
    for (int k = 0; k < H; k++) {
        float a = b2a[k];
#pragma unroll
        for (int j = 0; j < H; j++) a += z[j] * W2a[j * H + k];
        tv[k] = fmaxf(a, 0.f);
    }
    int g = batch[n];
#pragma unroll
    for (int j = 0; j < H; j++) {
        float a = b2b[j];
#pragma unroll
        for (int k = 0; k < H; k++) a += tv[k] * W2b[k * H + j];
        atomicAdd(&sums[(size_t)g * H + j], a);
    }
    atomicAdd(&counts[g], 1.f);
}
__global__ void finalF(const float* __restrict__ sums, const float* __restrict__ counts,
                       const float* __restrict__ Wfc, const float* __restrict__ bfc,
                       float* __restrict__ out, int G) {
    int g = blockIdx.x * blockDim.x + threadIdx.x;
    if (g >= G) return;
    float c = fmaxf(counts[g], 1.f);
    float acc = bfc[0];
#pragma unroll
    for (int j = 0; j < H; j++) acc += (sums[(size_t)g * H + j] / c) * Wfc[j];
    out[g] = 1.f / (1.f + expf(-acc));
}

// ============================ LAUNCH ============================
extern "C" void kernel_launch(void* const* d_in, const int* in_sizes, int n_in,
                              void* d_out, int out_size, void* d_ws, size_t ws_size,
                              hipStream_t stream) {
    const float* x    = (const float*)d_in[0];
    const int*   ei   = (const int*)d_in[1];
    const int*   batch= (const int*)d_in[2];
    const float* W1a  = (const float*)d_in[3];
    const float* b1a  = (const float*)d_in[4];
    const float* W1b  = (const float*)d_in[5];
    const float* b1b  = (const float*)d_in[6];
    const float* W2a  = (const float*)d_in[7];
    const float* b2a  = (const float*)d_in[8];
    const float* W2b  = (const float*)d_in[9];
    const float* b2b  = (const float*)d_in[10];
    const float* Wfc  = (const float*)d_in[11];
    const float* bfc  = (const float*)d_in[12];

    const int N = in_sizes[0];
    const int E = in_sizes[1] / 2;
    const int G = out_size;
    const int NB = (N + 255) >> BSH;
    const int chunk = (E + NBLKA - 1) / NBLKA;
    const int B = 256;

    auto rnd4 = [](size_t v) { return (v + 3) & ~(size_t)3; };
    size_t o_cur  = 0;                                    // cursor/bucketCnt [1024] (zeroed)
    size_t o_sc   = 1024;                                 // sumsCnt [9G]           (zeroed)
    size_t zelems = o_sc + (size_t)9 * G;                 // ---- memset to here ----
    size_t o_ns   = rnd4(zelems);                         // nodeStart [NB*256+1]
    size_t o_h1   = rnd4(o_ns + ((size_t)NB << BSH) + 1); // h1 fp8 [2 words/node]
    size_t o_pk   = rnd4(o_h1 + ((size_t)NB << BSH) * 2); // packed [NB*BCAP]
    size_t total  = o_pk + (size_t)NB * BCAP;

    bool srcFits = (N <= (1 << 18));
    bool chunkFits = (chunk <= SCHK);
    bool capOK = ((size_t)E / NB) * 10 <= (size_t)BCAP * 9;
    if (NB <= 1024 && srcFits && chunkFits && capOK && ws_size >= total * 4) {
        int*      wsi = (int*)d_ws;
        float*    wsf = (float*)d_ws;
        unsigned* wsu = (unsigned*)d_ws;
        int*      cursor    = wsi + o_cur;
        float*    sumsCnt   = wsf + o_sc;
        int*      nodeStart = wsi + o_ns;
        uint2*    h1        = (uint2*)(wsu + o_h1);
        unsigned* packed    = wsu + o_pk;

        hipMemsetAsync(d_ws, 0, zelems * 4, stream);
        scatterK<<<NBLKA, BTH, 0, stream>>>(ei, E, NB, chunk, cursor, packed);
        sortL1K<<<NB, TS, 0, stream>>>(packed, cursor, x, N, W1a, b1a, W1b, b1b,
                                       nodeStart, h1);
        layer2K<<<NB, 1024, 0, stream>>>(packed, nodeStart, cursor, h1, N,
                                         W2a, b2a, W2b, b2b, batch, sumsCnt);
        finalK<<<(G + B - 1) / B, B, 0, stream>>>(sumsCnt, Wfc, bfc, (float*)d_out, G);
    } else {
        float* ws     = (float*)d_ws;
        float* agg1   = ws;
        float* agg2   = agg1 + (size_t)N;
        float* sums   = agg2 + (size_t)8 * N;
        float* counts = sums + (size_t)8 * G;
        float* h1     = counts + (size_t)G;
        hipMemsetAsync(ws, 0, ((size_t)9 * N + (size_t)9 * G) * sizeof(float), stream);
        edge_agg1<<<(E + B - 1) / B, B, 0, stream>>>(ei, x, agg1, E);
        node1F<<<(N + B - 1) / B, B, 0, stream>>>(x, agg1, W1a, b1a, W1b, b1b, h1, N);
        long long tot = (long long)E * H;
        edge_agg2<<<(int)((tot + B - 1) / B), B, 0, stream>>>(ei, h1, agg2, E);
        node2F<<<(N + B - 1) / B, B, 0, stream>>>(h1, agg2, W2a, b2a, W2b, b2b, batch,
                                                  sums, counts, N);
        finalF<<<(G + B - 1) / B, B, 0, stream>>>(sums, counts, Wfc, bfc, (float*)d_out, G);
    }
}